// Round 1
// baseline (1339.659 us; speedup 1.0000x reference)
//
#include <hip/hip_runtime.h>
#include <hip/hip_bf16.h>
#include <stdint.h>

// ---- problem dims ----
#define DETER 2048
#define STOCH 1024
#define ACT   12
#define HID   1024
#define RANK  16
#define BSZ   16384
#define K1P   1056   // 1036 padded to multiple of 32

typedef unsigned short u16;
typedef __attribute__((ext_vector_type(8))) short short8;   // 8 bf16 (4 VGPRs)
typedef __attribute__((ext_vector_type(4))) float f32x4;

// ---- helpers ----
__device__ __forceinline__ float bf2f(u16 u) {
  union { uint32_t i; float f; } c; c.i = ((uint32_t)u) << 16; return c.f;
}
__device__ __forceinline__ u16 f2bf(float f) {   // round-to-nearest-even
  union { float f; uint32_t u; } c; c.f = f;
  uint32_t r = ((c.u >> 16) & 1u) + 0x7fffu;
  return (u16)((c.u + r) >> 16);
}
__device__ __forceinline__ float sigmoidf_(float x) { return 1.f / (1.f + expf(-x)); }
__device__ __forceinline__ float softplusf_(float x) { return (x > 20.f) ? x : log1pf(expf(x)); }

__device__ __forceinline__ void gload_lds16(const void* g, void* l) {
  __builtin_amdgcn_global_load_lds((const __attribute__((address_space(1))) void*)g,
                                   (__attribute__((address_space(3))) void*)l, 16, 0, 0);
}

// ---- workspace layout (bytes) ----
#define SZ_WBT1 ((size_t)1024 * K1P * 2)
#define SZ_WBT2 ((size_t)DETER * HID * 2)
#define SZ_WBTG ((size_t)DETER * (2 * DETER) * 2)
#define SZ_XIN  ((size_t)BSZ * K1P * 2)
#define SZ_H    ((size_t)BSZ * HID * 2)
#define SZ_XPRE ((size_t)BSZ * HID * 4)
#define SZ_J    ((size_t)BSZ * (2 * DETER) * 2)

#define O_WBT1 ((size_t)0)
#define O_WBT2 (O_WBT1 + SZ_WBT1)
#define O_WBTG (O_WBT2 + SZ_WBT2)
#define O_WBTC (O_WBTG + SZ_WBTG)
#define O_E    (O_WBTC + SZ_WBTG)
#define O_DTV  (O_E + 8192)
#define O_XIN  (O_DTV + 8192)
#define O_H    (O_XIN + SZ_XIN)
#define O_XPRE (O_H + SZ_H)          // reused later by ssmA, then Gpre
#define O_J    (O_XPRE + SZ_XPRE)
#define O_CPRE O_XIN                 // reuses Xin+H region (dead after GEMM2)
#define O_SSMA O_XPRE
#define O_GPRE O_XPRE
#define WS_NEED (O_J + SZ_J)

// ---------------- prep: e = exp(-softplus(a_log)*dt), dtv = softplus(dt_p)+1e-4 ----------------
__global__ void prep_params(const float* __restrict__ a_log, const float* __restrict__ dt_p,
                            float* __restrict__ ev, float* __restrict__ dtv) {
  int j = blockIdx.x * 256 + threadIdx.x;
  if (j < DETER) {
    float dt = softplusf_(dt_p[j]) + 1e-4f;
    float a  = -softplusf_(a_log[j]);
    ev[j]  = expf(a * dt);
    dtv[j] = dt;
  }
}

// ---------------- transpose fp32 [K][N] -> bf16 [N][Kp], zero K-pad ----------------
__global__ void transpose_w(const float* __restrict__ in, u16* __restrict__ out,
                            int K, int N, int Kp) {
  __shared__ float tile[32][33];
  int k0 = blockIdx.x * 32, n0 = blockIdx.y * 32;
  int tx = threadIdx.x, ty = threadIdx.y;   // 32 x 8
  #pragma unroll
  for (int r = 0; r < 4; ++r) {
    int k = k0 + ty + r * 8;
    tile[ty + r * 8][tx] = (k < K) ? in[(size_t)k * N + n0 + tx] : 0.f;
  }
  __syncthreads();
  #pragma unroll
  for (int r = 0; r < 4; ++r) {
    int n = n0 + ty + r * 8;
    out[(size_t)n * Kp + k0 + tx] = f2bf(tile[tx][ty + r * 8]);
  }
}

// ---------------- build Xin bf16 [B][1056] = [stoch | a/max(|a|,1) | 0pad] ----------------
__global__ void build_xin(const float* __restrict__ stoch, const float* __restrict__ action,
                          u16* __restrict__ Xin) {
  int idx = blockIdx.x * 256 + threadIdx.x;
  if (idx >= BSZ * 132) return;
  int b = idx / 132, c = idx % 132;
  union { u16 us[8]; uint4 u; } pk;
  if (c < 128) {
    const float4* p = (const float4*)(stoch + (size_t)b * 1024 + c * 8);
    float4 x = p[0], y = p[1];
    pk.us[0] = f2bf(x.x); pk.us[1] = f2bf(x.y); pk.us[2] = f2bf(x.z); pk.us[3] = f2bf(x.w);
    pk.us[4] = f2bf(y.x); pk.us[5] = f2bf(y.y); pk.us[6] = f2bf(y.z); pk.us[7] = f2bf(y.w);
  } else {
    #pragma unroll
    for (int e = 0; e < 8; ++e) {
      int col = c * 8 + e - 1024;
      float v = 0.f;
      if (col < ACT) {
        float a = action[(size_t)b * ACT + col];
        v = a / fmaxf(fabsf(a), 1.f);
      }
      pk.us[e] = f2bf(v);
    }
  }
  *(uint4*)(Xin + (size_t)b * K1P + c * 8) = pk.u;
}

// ---------------- GEMM: C[M,N] = A[M,K](bf16) * Bt[N,K](bf16)^T, m97 128x128 structure ----------------
// EPI 0: outF = acc + bias (fp32)            (GEMM1 -> Xpre)
// EPI 1: inp=acc+bias; ssm=ssmA+dtv*inp; J=[bf16(ssm)|bf16(inp)]   (GEMM2 -> J)
// EPI 2: outH = bf16(acc + bias)             (GEMM3/4 -> Gpre/Cpre)
template <int EPI>
__global__ void gemm_bt(const u16* __restrict__ A, const u16* __restrict__ Bt,
                        int K, int N,
                        const float* __restrict__ bias,
                        const u16* __restrict__ ssmA, const float* __restrict__ dtv,
                        float* __restrict__ outF, u16* __restrict__ outH,
                        u16* __restrict__ J) {
  __shared__ __attribute__((aligned(16))) u16 sA[128 * 32];
  __shared__ __attribute__((aligned(16))) u16 sB[128 * 32];

  // XCD-aware swizzle: contiguous work chunks per XCD (nwg % 8 == 0 for all our grids)
  int nwg = gridDim.x * gridDim.y;
  int flat = blockIdx.y * gridDim.x + blockIdx.x;
  int q = nwg >> 3;
  int wg = (flat & 7) * q + (flat >> 3);
  int by = wg / gridDim.x, bx = wg % gridDim.x;

  int blockRow = by * 128, blockCol = bx * 128;
  int tid = threadIdx.x;
  int wid = tid >> 6, lane = tid & 63;
  int wr = wid >> 1, wc = wid & 1;         // 2x2 wave grid, 64x64 per wave
  int l16 = lane & 15, lq = lane >> 4;
  int srow = lane >> 2;                    // staging: row within 16-row chunk
  int scol = (lane & 3) * 8;               // staging: col (8 bf16 = 16B)

  f32x4 acc[4][4];
  #pragma unroll
  for (int i = 0; i < 4; ++i)
    #pragma unroll
    for (int j = 0; j < 4; ++j) acc[i][j] = (f32x4){0.f, 0.f, 0.f, 0.f};

  const u16* aP = A + (size_t)blockRow * K + scol;
  const u16* bP = Bt + (size_t)blockCol * K + scol;
  int c0 = wid * 2, c1 = wid * 2 + 1;

  for (int kk = 0; kk < K; kk += 32) {
    // stage A[128][32], Bt[128][32] via direct global->LDS (16B/lane, wave-uniform LDS base)
    gload_lds16(aP + (size_t)(c0 * 16 + srow) * K + kk, &sA[c0 * 512]);
    gload_lds16(aP + (size_t)(c1 * 16 + srow) * K + kk, &sA[c1 * 512]);
    gload_lds16(bP + (size_t)(c0 * 16 + srow) * K + kk, &sB[c0 * 512]);
    gload_lds16(bP + (size_t)(c1 * 16 + srow) * K + kk, &sB[c1 * 512]);
    __syncthreads();

    short8 af[4], bf[4];
    #pragma unroll
    for (int i = 0; i < 4; ++i)
      af[i] = *(const short8*)&sA[(wr * 64 + i * 16 + l16) * 32 + lq * 8];
    #pragma unroll
    for (int j = 0; j < 4; ++j)
      bf[j] = *(const short8*)&sB[(wc * 64 + j * 16 + l16) * 32 + lq * 8];
    #pragma unroll
    for (int i = 0; i < 4; ++i)
      #pragma unroll
      for (int j = 0; j < 4; ++j)
        acc[i][j] = __builtin_amdgcn_mfma_f32_16x16x32_bf16(af[i], bf[j], acc[i][j], 0, 0, 0);
    __syncthreads();
  }

  // epilogue: C/D layout col = lane&15, row = (lane>>4)*4 + reg  [verified m89/m91]
  #pragma unroll
  for (int i = 0; i < 4; ++i) {
    int row0 = blockRow + wr * 64 + i * 16 + lq * 4;
    #pragma unroll
    for (int j = 0; j < 4; ++j) {
      int col = blockCol + wc * 64 + j * 16 + l16;
      float bv = bias[col];
      float dv = (EPI == 1) ? dtv[col] : 0.f;
      #pragma unroll
      for (int r = 0; r < 4; ++r) {
        size_t row = (size_t)(row0 + r);
        float v = acc[i][j][r] + bv;
        if (EPI == 0) {
          outF[row * N + col] = v;
        } else if (EPI == 2) {
          outH[row * N + col] = f2bf(v);
        } else {
          float ssm = bf2f(ssmA[row * N + col]) + dv * v;
          J[row * (2 * N) + col]     = f2bf(ssm);
          J[row * (2 * N) + N + col] = f2bf(v);
        }
      }
    }
  }
}

// ---------------- rmsnorm + silu: Xpre fp32 [B][1024] -> H bf16 ----------------
__global__ void rmsnorm_silu_k(const float* __restrict__ X, const float* __restrict__ g1,
                               u16* __restrict__ H) {
  int b = blockIdx.x, t = threadIdx.x;   // 256 threads x 4 elems
  const float4* x4 = (const float4*)(X + (size_t)b * HID);
  float4 v = x4[t];
  float ss = v.x * v.x + v.y * v.y + v.z * v.z + v.w * v.w;
  #pragma unroll
  for (int m = 32; m >= 1; m >>= 1) ss += __shfl_xor(ss, m, 64);
  __shared__ float red[4];
  if ((t & 63) == 0) red[t >> 6] = ss;
  __syncthreads();
  float tot = red[0] + red[1] + red[2] + red[3];
  float rms = rsqrtf(tot * (1.f / HID) + 1e-4f);
  float4 g = ((const float4*)g1)[t];
  float z0 = v.x * rms * g.x, z1 = v.y * rms * g.y, z2 = v.z * rms * g.z, z3 = v.w * rms * g.w;
  union { u16 us[4]; uint2 u; } pk;
  pk.us[0] = f2bf(z0 * sigmoidf_(z0));
  pk.us[1] = f2bf(z1 * sigmoidf_(z1));
  pk.us[2] = f2bf(z2 * sigmoidf_(z2));
  pk.us[3] = f2bf(z3 * sigmoidf_(z3));
  *(uint2*)(H + (size_t)b * HID + t * 4) = pk.u;
}

// ---------------- low-rank mix: ssmA = e * (deter + (deter@Wu)@Wv), 4 rows/block ----------------
__global__ void mix_k(const float* __restrict__ deter, const float* __restrict__ Wu,
                      const float* __restrict__ Wv, const float* __restrict__ ev,
                      u16* __restrict__ ssmA) {
  __shared__ __attribute__((aligned(16))) float ld[4][DETER];
  __shared__ float part[16][16][4];   // [chunk][r][row]
  __shared__ float ts[4][16];
  int b0 = blockIdx.x * 4, t = threadIdx.x;
  #pragma unroll
  for (int rr = 0; rr < 4; ++rr) {
    const float4* src = (const float4*)(deter + (size_t)(b0 + rr) * DETER);
    ((float4*)ld[rr])[t]       = src[t];
    ((float4*)ld[rr])[t + 256] = src[t + 256];
  }
  __syncthreads();
  int r = t & 15, chunk = t >> 4;     // 16 chunks x 16 rank
  float accv[4] = {0.f, 0.f, 0.f, 0.f};
  for (int i = 0; i < 128; ++i) {
    int k = i * 16 + chunk;           // interleaved: conflict-free LDS, coalesced Wu
    float w = Wu[(size_t)k * RANK + r];
    #pragma unroll
    for (int rr = 0; rr < 4; ++rr) accv[rr] += ld[rr][k] * w;
  }
  #pragma unroll
  for (int rr = 0; rr < 4; ++rr) part[chunk][r][rr] = accv[rr];
  __syncthreads();
  if (t < 64) {
    int rr = t >> 4, r2 = t & 15;
    float s = 0.f;
    #pragma unroll
    for (int c2 = 0; c2 < 16; ++c2) s += part[c2][r2][rr];
    ts[rr][r2] = s;
  }
  __syncthreads();
  #pragma unroll
  for (int jj = 0; jj < 8; ++jj) {
    int j = jj * 256 + t;
    float wv[16];
    #pragma unroll
    for (int r2 = 0; r2 < 16; ++r2) wv[r2] = Wv[(size_t)r2 * DETER + j];
    float ej = ev[j];
    #pragma unroll
    for (int rr = 0; rr < 4; ++rr) {
      float m = ld[rr][j];
      #pragma unroll
      for (int r2 = 0; r2 < 16; ++r2) m += ts[rr][r2] * wv[r2];
      ssmA[(size_t)(b0 + rr) * DETER + j] = f2bf(ej * m);
    }
  }
}

// ---------------- final: gate/cand blend + rmsnorm(gn) -> fp32 out ----------------
__global__ void final_k(const u16* __restrict__ Gpre, const u16* __restrict__ Cpre,
                        const float* __restrict__ deter, const float* __restrict__ gn,
                        float* __restrict__ out) {
  int b = blockIdx.x, t = threadIdx.x;   // 256 threads x 8 elems
  size_t base = (size_t)b * DETER;
  union { uint4 u; u16 us[8]; } pg, pc;
  pg.u = ((const uint4*)(Gpre + base))[t];
  pc.u = ((const uint4*)(Cpre + base))[t];
  const float4* d4 = (const float4*)(deter + base);
  float4 d0 = d4[t * 2], d1 = d4[t * 2 + 1];
  float dv[8] = {d0.x, d0.y, d0.z, d0.w, d1.x, d1.y, d1.z, d1.w};
  float o[8];
  float ss = 0.f;
  #pragma unroll
  for (int e = 0; e < 8; ++e) {
    float g = sigmoidf_(bf2f(pg.us[e]));
    float c = tanhf(bf2f(pc.us[e]));
    o[e] = g * c + (1.f - g) * dv[e];
    ss += o[e] * o[e];
  }
  #pragma unroll
  for (int m = 32; m >= 1; m >>= 1) ss += __shfl_xor(ss, m, 64);
  __shared__ float red[4];
  if ((t & 63) == 0) red[t >> 6] = ss;
  __syncthreads();
  float tot = red[0] + red[1] + red[2] + red[3];
  float rms = rsqrtf(tot * (1.f / DETER) + 1e-4f);
  #pragma unroll
  for (int e = 0; e < 8; ++e)
    out[base + t * 8 + e] = o[e] * rms * gn[t * 8 + e];
}

// ---------------- launcher ----------------
extern "C" void kernel_launch(void* const* d_in, const int* in_sizes, int n_in,
                              void* d_out, int out_size, void* d_ws, size_t ws_size,
                              hipStream_t stream) {
  const float* stoch  = (const float*)d_in[0];
  const float* deter  = (const float*)d_in[1];
  const float* action = (const float*)d_in[2];
  const float* W1 = (const float*)d_in[3];
  const float* b1 = (const float*)d_in[4];
  const float* g1 = (const float*)d_in[5];
  const float* W2 = (const float*)d_in[6];
  const float* b2 = (const float*)d_in[7];
  const float* Wu = (const float*)d_in[8];
  const float* Wv = (const float*)d_in[9];
  const float* a_log = (const float*)d_in[10];
  const float* dt_p  = (const float*)d_in[11];
  const float* Wg = (const float*)d_in[12];
  const float* bg = (const float*)d_in[13];
  const float* Wc = (const float*)d_in[14];
  const float* bc = (const float*)d_in[15];
  const float* gn = (const float*)d_in[16];

  if (ws_size < WS_NEED) return;  // ws too small -> output stays poisoned (clear failure)

  char* ws = (char*)d_ws;
  u16*   Wbt1 = (u16*)(ws + O_WBT1);
  u16*   Wbt2 = (u16*)(ws + O_WBT2);
  u16*   WbtG = (u16*)(ws + O_WBTG);
  u16*   WbtC = (u16*)(ws + O_WBTC);
  float* ev   = (float*)(ws + O_E);
  float* dtv  = (float*)(ws + O_DTV);
  u16*   Xin  = (u16*)(ws + O_XIN);
  u16*   H    = (u16*)(ws + O_H);
  float* Xpre = (float*)(ws + O_XPRE);
  u16*   ssmA = (u16*)(ws + O_SSMA);
  u16*   Gpre = (u16*)(ws + O_GPRE);
  u16*   Cpre = (u16*)(ws + O_CPRE);
  u16*   J    = (u16*)(ws + O_J);
  float* out  = (float*)d_out;

  dim3 tb(256);

  prep_params<<<dim3(8), tb, 0, stream>>>(a_log, dt_p, ev, dtv);
  transpose_w<<<dim3(K1P / 32, 1024 / 32), dim3(32, 8), 0, stream>>>(W1, Wbt1, STOCH + ACT, HID, K1P);
  transpose_w<<<dim3(HID / 32, DETER / 32), dim3(32, 8), 0, stream>>>(W2, Wbt2, HID, DETER, HID);
  transpose_w<<<dim3((2 * DETER) / 32, DETER / 32), dim3(32, 8), 0, stream>>>(Wg, WbtG, 2 * DETER, DETER, 2 * DETER);
  transpose_w<<<dim3((2 * DETER) / 32, DETER / 32), dim3(32, 8), 0, stream>>>(Wc, WbtC, 2 * DETER, DETER, 2 * DETER);
  build_xin<<<dim3(BSZ * 132 / 256), tb, 0, stream>>>(stoch, action, Xin);

  // GEMM1: Xpre = Xin @ W1 + b1
  gemm_bt<0><<<dim3(HID / 128, BSZ / 128), tb, 0, stream>>>(
      Xin, Wbt1, K1P, HID, b1, nullptr, nullptr, Xpre, nullptr, nullptr);
  // H = silu(rmsnorm(Xpre, g1))
  rmsnorm_silu_k<<<dim3(BSZ), tb, 0, stream>>>(Xpre, g1, H);
  // ssmA = e * (deter + (deter@Wu)@Wv)   (overwrites Xpre region — after H consumed it)
  mix_k<<<dim3(BSZ / 4), tb, 0, stream>>>(deter, Wu, Wv, ev, ssmA);
  // GEMM2: inp = H @ W2 + b2 ; J = [ssmA + dt*inp | inp]
  gemm_bt<1><<<dim3(DETER / 128, BSZ / 128), tb, 0, stream>>>(
      H, Wbt2, HID, DETER, b2, ssmA, dtv, nullptr, nullptr, J);
  // GEMM3/4: Gpre = J @ Wg + bg ; Cpre = J @ Wc + bc
  gemm_bt<2><<<dim3(DETER / 128, BSZ / 128), tb, 0, stream>>>(
      J, WbtG, 2 * DETER, DETER, bg, nullptr, nullptr, nullptr, Gpre, nullptr);
  gemm_bt<2><<<dim3(DETER / 128, BSZ / 128), tb, 0, stream>>>(
      J, WbtC, 2 * DETER, DETER, bc, nullptr, nullptr, nullptr, Cpre, nullptr);
  // final blend + rmsnorm
  final_k<<<dim3(BSZ), tb, 0, stream>>>(Gpre, Cpre, deter, gn, out);
}